// Round 3
// baseline (383.879 us; speedup 1.0000x reference)
//
#include <hip/hip_runtime.h>
#include <cmath>

typedef _Float16 half_t;
typedef _Float16 half8 __attribute__((ext_vector_type(8)));
typedef _Float16 half4v __attribute__((ext_vector_type(4)));
typedef float float4v __attribute__((ext_vector_type(4)));

#define LOG2E 1.44269504088896340736f

#define GLDS16(g, l)                                                                   \
    __builtin_amdgcn_global_load_lds((const __attribute__((address_space(1))) void*)(g), \
                                     (__attribute__((address_space(3))) void*)(l), 16, 0, 0)

// raw barriers: no compiler-inserted vmcnt(0) drain (the __syncthreads trap)
#define BAR_LGKM() __asm__ volatile("s_waitcnt lgkmcnt(0)\n\ts_barrier" ::: "memory")
#define BAR_VM(n)  __asm__ volatile("s_waitcnt vmcnt(" #n ")\n\ts_barrier" ::: "memory")

// ---------------- cast fp32 -> fp16 ----------------
__global__ void cast_f32_f16(const float* __restrict__ in, half_t* __restrict__ out, int n) {
    int i = (blockIdx.x * blockDim.x + threadIdx.x) * 4;
    if (i >= n) return;
    float4 v = *(const float4*)(in + i);
    half4v o;
    o[0] = (half_t)v.x; o[1] = (half_t)v.y; o[2] = (half_t)v.z; o[3] = (half_t)v.w;
    *(half4v*)(out + i) = o;
}

// ---------------- transpose + cast: in fp32 [R][C] -> out fp16 [C][R] ----------------
__global__ void transpose_cast(const float* __restrict__ in, half_t* __restrict__ out, int R, int C) {
    __shared__ float tile[32][33];
    int c0 = blockIdx.x * 32, r0 = blockIdx.y * 32;
    int tx = threadIdx.x, ty = threadIdx.y; // block (32,8)
    for (int p = 0; p < 4; p++) {
        int r = r0 + ty + p * 8;
        tile[ty + p * 8][tx] = in[(size_t)r * C + c0 + tx];
    }
    __syncthreads();
    for (int p = 0; p < 4; p++) {
        int c = c0 + ty + p * 8;
        out[(size_t)c * R + r0 + tx] = (half_t)tile[tx][ty + p * 8];
    }
}

// =====================================================================================
// QKV GEMM: 256x256 tile, BK=64, 8-wave, 2 phases/tile, READS PIPELINED ONE PHASE AHEAD.
// Phase = { lgkm(0); bar; issue next-phase ds_reads (other reg set) + 2 stages;
//           MFMA x32; vmcnt(4); bar }  -> LDS drain overlaps the MFMA window.
// Register double-buffer: afA (A0-half), afB (A1-half), bX/bY (B, 2-tile parity unroll
// so all frag indexing is compile-time, rule #20). 4 barriers/tile (was 8).
// vmcnt: 4 GLDS/phase; vmcnt(4) at phase end commits stages issued 2 phases prior
// (+ barrier = cross-wave commit). Tail: vmcnt(0) once staging stops.
// Swizzles (verified r2, conflicts=0): A chunk^(row&7) via pre-swizzled source;
// B stored pos (c+(row>>1))&3 via source bc=((t&3)-(t>>3))&3, read posq=(quad+(lrow>>1))&3.
// =====================================================================================
__global__ __launch_bounds__(512, 2) void gemm_qkv(
    const half_t* __restrict__ A,   // [M][K] = xh
    const half_t* __restrict__ Bt,  // [N][K] = Wqt
    const float* __restrict__ bias, // [N]
    const float* __restrict__ wq, const float* __restrict__ wk,
    half_t* __restrict__ Qh, half_t* __restrict__ Kh, half_t* __restrict__ Vt,
    int M, int N, int K)
{
    __shared__ __align__(16) half_t As[2][2][128 * 64];  // [buf][mhalf]
    __shared__ __align__(16) half_t Bs[2][2][256 * 32];  // [buf][khalf]

    int t = threadIdx.x;
    int lane = t & 63, w = t >> 6;
    int lrow = lane & 15, quad = lane >> 4;
    int wm = w >> 2, wn = w & 3;

    // XCD-aware swizzle (grid 384 % 8 == 0 -> simple form is bijective)
    int cpx = gridDim.x >> 3;
    int bid = blockIdx.x;
    int wg = (bid & 7) * cpx + (bid >> 3);
    int nbn = N >> 8;
    int mb = wg / nbn, nb = wg % nbn;
    int m0 = mb << 8, n0 = nb << 8;

    // ---- staging source pointers (source pre-swizzled to match read swizzles) ----
    int ar = t >> 3;                       // A: 64 rows/round, 8 chunks of 16B
    int ac = (t & 7) ^ (ar & 7);           // inverse of chunk ^ (row&7)
    const half_t* gAbase = A + (size_t)(m0 + ar) * K + ac * 8;
    int br = t >> 2;                       // B: 128 rows/round, 4 chunks of 16B
    int bc = ((t & 3) - (t >> 3)) & 3;     // inverse of c' = (c + (row>>1)) & 3
    const half_t* gBbase = Bt + (size_t)(n0 + br) * K + bc * 8;

    auto stageA = [&](int buf, int a, int T) {
        const half_t* s = gAbase + (size_t)a * 128 * K + T * 64;
        GLDS16(s,                  &As[buf][a][w * 512]);
        GLDS16(s + (size_t)64 * K, &As[buf][a][4096 + w * 512]);
    };
    auto stageB = [&](int buf, int kh, int T) {
        const half_t* s = gBbase + T * 64 + kh * 32;
        GLDS16(s,                   &Bs[buf][kh][w * 512]);
        GLDS16(s + (size_t)128 * K, &Bs[buf][kh][4096 + w * 512]);
    };

    // ---- ds_read offsets ----
    int sw = lrow & 7;
    int cx0 = ((0 + quad) ^ sw) * 8;       // A kk=0 chunk, swizzled
    int cx1 = ((4 + quad) ^ sw) * 8;       // A kk=1 chunk, swizzled
    int posq = (quad + (lrow >> 1)) & 3;   // B stored chunk position
    int aoffs = (wm * 64 + lrow) * 64;
    int boffs = (wn * 64 + lrow) * 32 + posq * 8;

    half8 afA[4][2], afB[4][2];            // A fragments: mhalf 0 / mhalf 1
    half8 bX0[4], bX1[4], bY0[4], bY1[4];  // B fragments, tile-parity double buffer
    float4v acc[2][4][4] = {};             // [ahalf][mi][ni]

    auto loadAf = [&](int buf, int a, half8 (&dst)[4][2]) {
        #pragma unroll
        for (int mi = 0; mi < 4; mi++) {
            dst[mi][0] = *(const half8*)(&As[buf][a][aoffs + mi * 1024 + cx0]);
            dst[mi][1] = *(const half8*)(&As[buf][a][aoffs + mi * 1024 + cx1]);
        }
    };
    auto loadBf = [&](int buf, int kh, half8 (&dst)[4]) {
        #pragma unroll
        for (int ni = 0; ni < 4; ni++)
            dst[ni] = *(const half8*)(&Bs[buf][kh][boffs + ni * 512]);
    };

#define MFMA32(AF, B0A, B1A, AI)                                                  \
    do { _Pragma("unroll")                                                        \
        for (int mi = 0; mi < 4; mi++) { _Pragma("unroll")                        \
            for (int ni = 0; ni < 4; ni++) {                                      \
                acc[AI][mi][ni] = __builtin_amdgcn_mfma_f32_16x16x32_f16(         \
                    AF[mi][0], B0A[ni], acc[AI][mi][ni], 0, 0, 0);                \
                acc[AI][mi][ni] = __builtin_amdgcn_mfma_f32_16x16x32_f16(         \
                    AF[mi][1], B1A[ni], acc[AI][mi][ni], 0, 0, 0);                \
            } } } while (0)

#define TILE_BODY(T_, BC0, BC1, BN0, BN1)                                         \
    do {                                                                          \
        const int Tb = (T_);                                                      \
        const int bufb = Tb & 1, nbufb = bufb ^ 1;                                \
        /* ---- P0: MFMA A0xK64; prefetch-read A1; stage (buf, T+2) pair 0 ----*/ \
        __asm__ volatile("s_waitcnt lgkmcnt(0)" ::: "memory");                    \
        __builtin_amdgcn_sched_barrier(0);                                        \
        __asm__ volatile("s_barrier" ::: "memory");                               \
        loadAf(bufb, 1, afB);                                                     \
        if (Tb + 2 < nk) { stageA(bufb, 0, Tb + 2); stageB(bufb, 0, Tb + 2); }    \
        __builtin_amdgcn_sched_barrier(0);                                        \
        __builtin_amdgcn_s_setprio(1);                                            \
        MFMA32(afA, BC0, BC1, 0);                                                 \
        __builtin_amdgcn_s_setprio(0);                                            \
        __builtin_amdgcn_sched_barrier(0);                                        \
        if (Tb + 2 < nk) { __asm__ volatile("s_waitcnt vmcnt(4)" ::: "memory"); } \
        else             { __asm__ volatile("s_waitcnt vmcnt(0)" ::: "memory"); } \
        __asm__ volatile("s_barrier" ::: "memory");                               \
        /* ---- P1: MFMA A1xK64; prefetch-read next tile A0+B; stage pair 1 --*/  \
        __asm__ volatile("s_waitcnt lgkmcnt(0)" ::: "memory");                    \
        __builtin_amdgcn_sched_barrier(0);                                        \
        __asm__ volatile("s_barrier" ::: "memory");                               \
        if (Tb + 1 < nk) {                                                        \
            loadAf(nbufb, 0, afA);                                                \
            loadBf(nbufb, 0, BN0);                                                \
            loadBf(nbufb, 1, BN1);                                                \
        }                                                                         \
        if (Tb + 2 < nk) { stageA(bufb, 1, Tb + 2); stageB(bufb, 1, Tb + 2); }    \
        __builtin_amdgcn_sched_barrier(0);                                        \
        __builtin_amdgcn_s_setprio(1);                                            \
        MFMA32(afB, BC0, BC1, 1);                                                 \
        __builtin_amdgcn_s_setprio(0);                                            \
        __builtin_amdgcn_sched_barrier(0);                                        \
        if (Tb + 2 < nk) { __asm__ volatile("s_waitcnt vmcnt(4)" ::: "memory"); } \
        else             { __asm__ volatile("s_waitcnt vmcnt(0)" ::: "memory"); } \
        __asm__ volatile("s_barrier" ::: "memory");                               \
    } while (0)

    int nk = K >> 6;   // K-tiles of 64 (nk even)

    // ---- prologue: stage tiles 0 and 1 (16 GLDS), commit tile 0, read tile 0 ----
    stageA(0, 0, 0); stageB(0, 0, 0); stageA(0, 1, 0); stageB(0, 1, 0);
    stageA(1, 0, 1); stageB(1, 0, 1); stageA(1, 1, 1); stageB(1, 1, 1);
    __asm__ volatile("s_waitcnt vmcnt(8)" ::: "memory");   // tile0 landed
    __asm__ volatile("s_barrier" ::: "memory");
    loadAf(0, 0, afA);
    loadBf(0, 0, bX0);
    loadBf(0, 1, bX1);

    for (int T0 = 0; T0 < nk; T0 += 2) {
        TILE_BODY(T0,     bX0, bX1, bY0, bY1);
        TILE_BODY(T0 + 1, bY0, bY1, bX0, bX1);
    }

    // ---- epilogue: per-wave 64-col group = one head (Q/K rmsnorm) or V chunk ----
    int nglob = n0 + wn * 64;
    if (nglob < 2048) {
        int isK = nglob >> 10;
        int h = (nglob >> 6) & 15;
        const float* wv = isK ? wk : wq;
        half_t* dst = isK ? Kh : Qh;
        float post = isK ? 1.0f : LOG2E;   // pre-scale Q so attn works in log2 domain
        #pragma unroll
        for (int a = 0; a < 2; a++) {
            #pragma unroll
            for (int mi = 0; mi < 4; mi++) {
                #pragma unroll
                for (int r = 0; r < 4; r++) {
                    int gr = m0 + a * 128 + wm * 64 + mi * 16 + quad * 4 + r;
                    float v[4]; float ss = 0.f;
                    #pragma unroll
                    for (int ni = 0; ni < 4; ni++) {
                        v[ni] = acc[a][mi][ni][r] + bias[nglob + ni * 16 + lrow];
                        ss += v[ni] * v[ni];
                    }
                    ss += __shfl_xor(ss, 1);
                    ss += __shfl_xor(ss, 2);
                    ss += __shfl_xor(ss, 4);
                    ss += __shfl_xor(ss, 8);
                    float rr = rsqrtf(ss * (1.0f / 64.0f) + 1e-6f) * post;
                    int bb = gr >> 11, s = gr & 2047;
                    size_t rowbase = ((size_t)((bb * 16 + h) * 2048 + s)) * 64;
                    #pragma unroll
                    for (int ni = 0; ni < 4; ni++) {
                        int d = ni * 16 + lrow;
                        dst[rowbase + d] = (half_t)(v[ni] * rr * wv[d]);
                    }
                }
            }
        }
    } else {
        // V part: store transposed into Vt[bh][d][s]
        #pragma unroll
        for (int a = 0; a < 2; a++) {
            #pragma unroll
            for (int mi = 0; mi < 4; mi++) {
                int gr = m0 + a * 128 + wm * 64 + mi * 16 + quad * 4;   // s-base, 4-aligned
                int bb = gr >> 11, s = gr & 2047;
                #pragma unroll
                for (int ni = 0; ni < 4; ni++) {
                    int dg = nglob + ni * 16 + lrow - 2048;   // 0..1023
                    float bv = bias[nglob + ni * 16 + lrow];
                    half4v oh;
                    #pragma unroll
                    for (int r = 0; r < 4; r++) oh[r] = (half_t)(acc[a][mi][ni][r] + bv);
                    *(half4v*)(Vt + ((size_t)((bb * 16 + (dg >> 6)) * 64 + (dg & 63))) * 2048 + s) = oh;
                }
            }
        }
    }
#undef TILE_BODY
#undef MFMA32
}

// ---------------- GEMM: C[M][N] = A[M][K] * Bt[N][K]^T + bias (output proj) ----------
// (r10 config: triple-buffered GLDS, raw barriers, bank-swizzle, 3 waves/SIMD)
template <int MODE>
__global__ __launch_bounds__(256, 3) void gemm_f16(
    const half_t* __restrict__ A,   // [M][K]
    const half_t* __restrict__ Bt,  // [N][K]
    const float* __restrict__ bias, // [N]
    void* __restrict__ Cout,
    int M, int N, int K,
    const float* __restrict__ wq, const float* __restrict__ wk,
    half_t* __restrict__ Qh, half_t* __restrict__ Kh)
{
    __shared__ __align__(16) half_t As[3][128 * 32];
    __shared__ __align__(16) half_t Bs[3][128 * 32];
    int t = threadIdx.x;
    int lane = t & 63, w = t >> 6;
    int m0 = blockIdx.x * 128, n0 = blockIdx.y * 128;
    int wm = (w >> 1) * 64, wn = (w & 1) * 64;
    int lrow = lane & 15, quad = lane >> 4;

    int lc = ((t & 3) - (t >> 3)) & 3;
    const half_t* gA = A  + (size_t)(m0 + (t >> 2)) * K + lc * 8;
    const half_t* gB = Bt + (size_t)(n0 + (t >> 2)) * K + lc * 8;
    half_t* ldsA[3] = { &As[0][w * 512], &As[1][w * 512], &As[2][w * 512] };
    half_t* ldsB[3] = { &Bs[0][w * 512], &Bs[1][w * 512], &Bs[2][w * 512] };

    int posq = (quad + (lrow >> 1)) & 3;

    float4v acc[4][4] = {};

    GLDS16(gA,                       ldsA[0]);
    GLDS16(gA + (size_t)64 * K,      ldsA[0] + 2048);
    GLDS16(gB,                       ldsB[0]);
    GLDS16(gB + (size_t)64 * K,      ldsB[0] + 2048);
    GLDS16(gA + 32,                  ldsA[1]);
    GLDS16(gA + (size_t)64 * K + 32, ldsA[1] + 2048);
    GLDS16(gB + 32,                  ldsB[1]);
    GLDS16(gB + (size_t)64 * K + 32, ldsB[1] + 2048);

    int nk = K >> 5;
    for (int ki = 0; ki < nk; ki++) {
        int cur = ki % 3, pre = (ki + 2) % 3;
        BAR_LGKM();
        if (ki + 2 < nk) {
            int kp = (ki + 2) << 5;
            GLDS16(gA + kp,                  ldsA[pre]);
            GLDS16(gA + (size_t)64 * K + kp, ldsA[pre] + 2048);
            GLDS16(gB + kp,                  ldsB[pre]);
            GLDS16(gB + (size_t)64 * K + kp, ldsB[pre] + 2048);
            BAR_VM(8);
        } else if (ki + 1 < nk) {
            BAR_VM(4);
        } else {
            BAR_VM(0);
        }
        half8 af[4], bf[4];
        for (int i = 0; i < 4; i++) af[i] = *(const half8*)(&As[cur][(wm + i * 16 + lrow) * 32 + posq * 8]);
        for (int i = 0; i < 4; i++) bf[i] = *(const half8*)(&Bs[cur][(wn + i * 16 + lrow) * 32 + posq * 8]);
        for (int mi = 0; mi < 4; mi++)
            for (int ni = 0; ni < 4; ni++)
                acc[mi][ni] = __builtin_amdgcn_mfma_f32_16x16x32_f16(af[mi], bf[ni], acc[mi][ni], 0, 0, 0);
    }

    if (MODE == 0) {
        float* out = (float*)Cout;
        for (int mi = 0; mi < 4; mi++)
            for (int ni = 0; ni < 4; ni++)
                for (int r = 0; r < 4; r++) {
                    int gr = m0 + wm + mi * 16 + quad * 4 + r;
                    int gc = n0 + wn + ni * 16 + lrow;
                    out[(size_t)gr * N + gc] = acc[mi][ni][r] + bias[gc];
                }
    } else {
        int nglob = n0 + wn;            // 64-aligned; one head per wave
        if (nglob < 2048) {
            int isK = nglob >> 10;
            int h = (nglob >> 6) & 15;
            const float* wv = isK ? wk : wq;
            half_t* dst = isK ? Kh : Qh;
            float post = isK ? 1.0f : LOG2E;
            for (int mi = 0; mi < 4; mi++)
                for (int r = 0; r < 4; r++) {
                    int gr = m0 + wm + mi * 16 + quad * 4 + r;
                    float v[4]; float ss = 0.f;
                    for (int ni = 0; ni < 4; ni++) {
                        v[ni] = acc[mi][ni][r] + bias[nglob + ni * 16 + lrow];
                        ss += v[ni] * v[ni];
                    }
                    ss += __shfl_xor(ss, 1);
                    ss += __shfl_xor(ss, 2);
                    ss += __shfl_xor(ss, 4);
                    ss += __shfl_xor(ss, 8);
                    float rr = rsqrtf(ss * (1.0f / 64.0f) + 1e-6f) * post;
                    int bb = gr >> 11, s = gr & 2047;
                    size_t rowbase = ((size_t)((bb * 16 + h) * 2048 + s)) * 64;
                    for (int ni = 0; ni < 4; ni++) {
                        int d = ni * 16 + lrow;
                        dst[rowbase + d] = (half_t)(v[ni] * rr * wv[d]);
                    }
                }
        } else {
            half_t* Vt = (half_t*)Cout;
            for (int mi = 0; mi < 4; mi++) {
                int gr = m0 + wm + mi * 16 + quad * 4;
                int bb = gr >> 11, s = gr & 2047;
                for (int ni = 0; ni < 4; ni++) {
                    int dg = nglob + ni * 16 + lrow - 2048;
                    float bv = bias[nglob + ni * 16 + lrow];
                    half4v oh;
                    for (int r = 0; r < 4; r++) oh[r] = (half_t)(acc[mi][ni][r] + bv);
                    *(half4v*)(Vt + ((size_t)((bb * 16 + (dg >> 6)) * 64 + (dg & 63))) * 2048 + s) = oh;
                }
            }
        }
    }
}

// ---------------- Flash attention, causal, no scale (Q pre-scaled by LOG2E) --
// 8 waves / 128 q-rows, paired q-tiles (i,15-i), grid (bh, pair) for XCD L2.
__global__ __launch_bounds__(512, 4) void attn(
    const half_t* __restrict__ Qh, const half_t* __restrict__ Kh, const half_t* __restrict__ Vt,
    half_t* __restrict__ Z)
{
    __shared__ __align__(16) half_t Ks[2][128 * 64];  // [buf][key][d], pos = chunk ^ (key&7)
    __shared__ __align__(16) half_t Vs[2][64 * 128];  // [buf][d][key], pos = chunk ^ (d&7)
    __shared__ __align__(16) half_t Ps[8][16 * 64];   // per-wave [q][key-half]

    int bh = blockIdx.x;
    int b = bh >> 4, h = bh & 15;
    int t = threadIdx.x, lane = t & 63, w = t >> 6;
    int lrow = lane & 15, quad = lane >> 4;

    int scc = (lane & 7) ^ ((lane >> 3) & 7);
    const half_t* gK0 = Kh + ((size_t)bh * 2048 + w * 16 + (lane >> 3)) * 64 + scc * 8;
    int vr0 = w * 8 + (lane >> 4);
    int vc0 = (lane & 15) ^ (lane >> 4);
    int vc1 = (lane & 15) ^ ((lane >> 4) + 4);
    const half_t* gV0 = Vt + ((size_t)bh * 64 + vr0) * 2048 + vc0 * 8;
    const half_t* gV1 = Vt + ((size_t)bh * 64 + vr0 + 4) * 2048 + vc1 * 8;
    half_t* ldsK[2] = { &Ks[0][w * 1024], &Ks[1][w * 1024] };
    half_t* ldsV[2] = { &Vs[0][w * 1024], &Vs[1][w * 1024] };

    int sw = lrow & 7;
    int cA = (quad ^ sw) * 8;
    int cB = ((quad + 4) ^ sw) * 8;
    half_t* PsW = &Ps[w][lrow * 64];

    for (int pass = 0; pass < 2; pass++) {
        int qt = pass ? (15 - (int)blockIdx.y) : (int)blockIdx.y;
        int q0w = qt * 128 + w * 16;

        const half_t* Qbase = Qh + ((size_t)bh * 2048 + q0w + lrow) * 64;
        half8 qf0 = *(const half8*)(Qbase + quad * 8);
        half8 qf1 = *(const half8*)(Qbase + 32 + quad * 8);

        float4v ot[4] = {};
        float m = -__builtin_inff(), l = 0.f;

        int nt = qt + 1;
        __syncthreads();
        GLDS16(gK0,       ldsK[0]);
        GLDS16(gK0 + 512, ldsK[0] + 512);
        GLDS16(gV0,       ldsV[0]);
        GLDS16(gV1,       ldsV[0] + 512);

        for (int kt = 0; kt < nt; kt++) {
            int cur = kt & 1, nxt = cur ^ 1;
            int kb = kt * 128;
            BAR_LGKM();
            if (kt + 1 < nt) {
                size_t ko = (size_t)(kb + 128);
                GLDS16(gK0 + ko * 64,       ldsK[nxt]);
                GLDS16(gK0 + ko * 64 + 512, ldsK[nxt] + 512);
                GLDS16(gV0 + ko,            ldsV[nxt]);
                GLDS16(gV1 + ko,            ldsV[nxt] + 512);
                BAR_VM(4);
            } else {
                BAR_VM(0);
            }

            float4v st[8];
            for (int f = 0; f < 8; f++) {
                float4v z = {};
                const half_t* kr = &Ks[cur][(f * 16 + lrow) * 64];
                half8 k0 = *(const half8*)(kr + cA);
                half8 k1 = *(const half8*)(kr + cB);
                z = __builtin_amdgcn_mfma_f32_16x16x32_f16(k0, qf0, z, 0, 0, 0);
                z = __builtin_amdgcn_mfma_f32_16x16x32_f16(k1, qf1, z, 0, 0, 0);
                st[f] = z;
            }
            if (kb + 127 > q0w) {
                int qabs = q0w + lrow;
                for (int f = 0; f < 8; f++)
                    for (int r = 0; r < 4; r++) {
                        int key = kb + f * 16 + quad * 4 + r;
                        if (key > qabs) st[f][r] = -__builtin_inff();
                    }
            }
            float tm = st[0][0];
            for (int f = 0; f < 8; f++)
                for (int r = 0; r < 4; r++) tm = fmaxf(tm, st[f][r]);
            tm = fmaxf(tm, __shfl_xor(tm, 16));
            tm = fmaxf(tm, __shfl_xor(tm, 32));
            float mn = fmaxf(m, tm);
            float alpha = __builtin_amdgcn_exp2f(m - mn);
            m = mn;
            float rs = 0.f;
            uint2 pw1[4];
            for (int f = 0; f < 8; f++) {
                float p0 = __builtin_amdgcn_exp2f(st[f][0] - mn);
                float p1 = __builtin_amdgcn_exp2f(st[f][1] - mn);
                float p2 = __builtin_amdgcn_exp2f(st[f][2] - mn);
                float p3 = __builtin_amdgcn_exp2f(st[f][3] - mn);
                rs += (p0 + p1) + (p2 + p3);
                uint2 pw;
                pw.x = __builtin_bit_cast(unsigned, __builtin_amdgcn_cvt_pkrtz(p0, p1));
                pw.y = __builtin_bit_cast(unsigned, __builtin_amdgcn_cvt_pkrtz(p2, p3));
                if (f < 4) {
                    int cc = (2 * f + (quad >> 1)) ^ sw;
                    *(uint2*)(PsW + cc * 8 + (quad & 1) * 4) = pw;
                } else {
                    pw1[f - 4] = pw;
                }
            }
            rs += __shfl_xor(rs, 16);
            rs += __shfl_xor(rs, 32);
            l = l * alpha + rs;
            for (int f2 = 0; f2 < 4; f2++)
                for (int r = 0; r < 4; r++) ot[f2][r] *= alpha;

            __asm__ volatile("s_waitcnt lgkmcnt(0)" ::: "memory");
            half8 p0v = *(const half8*)(PsW + cA);
            half8 p1v = *(const half8*)(PsW + cB);
            for (int f2 = 0; f2 < 4; f2++) {
                int row = f2 * 16 + lrow;
                half8 v0 = *(const half8*)(&Vs[cur][row * 128 + ((quad ^ sw)) * 8]);
                half8 v1 = *(const half8*)(&Vs[cur][row * 128 + (((4 + quad) ^ sw)) * 8]);
                ot[f2] = __builtin_amdgcn_mfma_f32_16x16x32_f16(v0, p0v, ot[f2], 0, 0, 0);
                ot[f2] = __builtin_amdgcn_mfma_f32_16x16x32_f16(v1, p1v, ot[f2], 0, 0, 0);
            }
            for (int f = 0; f < 4; f++) {
                int cc = (2 * f + (quad >> 1)) ^ sw;
                *(uint2*)(PsW + cc * 8 + (quad & 1) * 4) = pw1[f];
            }
            __asm__ volatile("s_waitcnt lgkmcnt(0)" ::: "memory");
            half8 p2v = *(const half8*)(PsW + cA);
            half8 p3v = *(const half8*)(PsW + cB);
            for (int f2 = 0; f2 < 4; f2++) {
                int row = f2 * 16 + lrow;
                half8 v2 = *(const half8*)(&Vs[cur][row * 128 + (((8 + quad) ^ sw)) * 8]);
                half8 v3 = *(const half8*)(&Vs[cur][row * 128 + (((12 + quad) ^ sw)) * 8]);
                ot[f2] = __builtin_amdgcn_mfma_f32_16x16x32_f16(v2, p2v, ot[f2], 0, 0, 0);
                ot[f2] = __builtin_amdgcn_mfma_f32_16x16x32_f16(v3, p3v, ot[f2], 0, 0, 0);
            }
        }

        float inv = 1.0f / l;
        size_t base = ((size_t)(b * 2048) + q0w + lrow) * 1024 + h * 64;
        for (int f2 = 0; f2 < 4; f2++) {
            half4v oh;
            for (int r = 0; r < 4; r++) oh[r] = (half_t)(ot[f2][r] * inv);
            *(half4v*)(Z + base + f2 * 16 + quad * 4) = oh;
        }
    }
}

// ---------------- launch ----------------
extern "C" void kernel_launch(void* const* d_in, const int* in_sizes, int n_in,
                              void* d_out, int out_size, void* d_ws, size_t ws_size,
                              hipStream_t stream)
{
    const float* x     = (const float*)d_in[0];
    // d_in[1] = mask (causal, known analytically) - unused
    const float* W_qkv = (const float*)d_in[2];
    const float* b_qkv = (const float*)d_in[3];
    const float* W_o   = (const float*)d_in[4];
    const float* b_o   = (const float*)d_in[5];
    const float* wq    = (const float*)d_in[6];
    const float* wk    = (const float*)d_in[7];
    float* out = (float*)d_out;

    char* ws = (char*)d_ws;
    half_t* xh   = (half_t*)(ws);                     // 16 MB (reused as zh after attn)
    half_t* Wqt  = (half_t*)(ws + (16ull << 20));     // 6 MB
    half_t* Wot  = (half_t*)(ws + (22ull << 20));     // 2 MB
    half_t* Qh   = (half_t*)(ws + (40ull << 20));     // 16 MB
    half_t* Kh   = (half_t*)(ws + (56ull << 20));     // 16 MB
    half_t* Vt   = (half_t*)(ws + (72ull << 20));     // 16 MB
    half_t* zh   = xh;

    cast_f32_f16<<<8192, 256, 0, stream>>>(x, xh, 8192 * 1024);
    transpose_cast<<<dim3(96, 32), dim3(32, 8), 0, stream>>>(W_qkv, Wqt, 1024, 3072);
    transpose_cast<<<dim3(32, 32), dim3(32, 8), 0, stream>>>(W_o, Wot, 1024, 1024);
    gemm_qkv<<<384, 512, 0, stream>>>(xh, Wqt, b_qkv, wq, wk, Qh, Kh, Vt, 8192, 3072, 1024);
    attn<<<dim3(64, 8), 512, 0, stream>>>(Qh, Kh, Vt, zh);
    gemm_f16<0><<<dim3(64, 8), 256, 0, stream>>>(zh, Wot, b_o, out, 8192, 1024, 1024,
                                                 nullptr, nullptr, nullptr, nullptr);
}

// Round 5
// 273.337 us; speedup vs baseline: 1.4044x; 1.4044x over previous
//
#include <hip/hip_runtime.h>
#include <cmath>

typedef _Float16 half_t;
typedef _Float16 half8 __attribute__((ext_vector_type(8)));
typedef _Float16 half4v __attribute__((ext_vector_type(4)));
typedef float float4v __attribute__((ext_vector_type(4)));

#define LOG2E 1.44269504088896340736f

#define GLDS16(g, l)                                                                   \
    __builtin_amdgcn_global_load_lds((const __attribute__((address_space(1))) void*)(g), \
                                     (__attribute__((address_space(3))) void*)(l), 16, 0, 0)

// raw barriers: no compiler-inserted vmcnt(0) drain (the __syncthreads trap)
#define BAR_LGKM() __asm__ volatile("s_waitcnt lgkmcnt(0)\n\ts_barrier" ::: "memory")
#define BAR_VM(n)  __asm__ volatile("s_waitcnt vmcnt(" #n ")\n\ts_barrier" ::: "memory")

// ---------------- cast fp32 -> fp16 ----------------
__global__ void cast_f32_f16(const float* __restrict__ in, half_t* __restrict__ out, int n) {
    int i = (blockIdx.x * blockDim.x + threadIdx.x) * 4;
    if (i >= n) return;
    float4 v = *(const float4*)(in + i);
    half4v o;
    o[0] = (half_t)v.x; o[1] = (half_t)v.y; o[2] = (half_t)v.z; o[3] = (half_t)v.w;
    *(half4v*)(out + i) = o;
}

// ---------------- transpose + cast: in fp32 [R][C] -> out fp16 [C][R] ----------------
__global__ void transpose_cast(const float* __restrict__ in, half_t* __restrict__ out, int R, int C) {
    __shared__ float tile[32][33];
    int c0 = blockIdx.x * 32, r0 = blockIdx.y * 32;
    int tx = threadIdx.x, ty = threadIdx.y; // block (32,8)
    for (int p = 0; p < 4; p++) {
        int r = r0 + ty + p * 8;
        tile[ty + p * 8][tx] = in[(size_t)r * C + c0 + tx];
    }
    __syncthreads();
    for (int p = 0; p < 4; p++) {
        int c = c0 + ty + p * 8;
        out[(size_t)c * R + r0 + tx] = (half_t)tile[tx][ty + p * 8];
    }
}

// =====================================================================================
// QKV GEMM: 256x256 tile, BK=64, 8-wave. 4 phases/K-tile, each phase = one (mhalf,kk)
// pair: 16 MFMA + <=8 ds_read_b128 issued ONE PHASE AHEAD into the alternate reg set.
// Register budget (the r3 spill lesson): acc 128 + af0/af1 32 + b0/b1 32 = 192 live.
//   phase->regs (static, no parity unroll): p0:(af0=A0k0,b0,acc0) p1:(af1=A1k0,b0,acc1)
//                                           p2:(af0=A0k1,b1,acc0) p3:(af1=A1k1,b1,acc1)
//   reads:  p0: A1k0->af1, B1->b1 | p1: A0k1->af0 | p2: A1k1->af1, B0(T+1)->b0 |
//           p3: A0k0(T+1)->af0        (b regs rotate in place after last use)
//   stages (region staged only after its last read, 2 GLDS/phase):
//           p0: B0(T+2) | p1: B1(T+2) | p2: A0(T+2) | p3: A1(T+2)
//   vmcnt(6) at each phase end commits the stage issued 3 phases prior; prologue order
//   [B0,B1,A0,A1]x2 makes commits land exactly when p2(0)/p3(0)/p0(1) need them.
//   Prologue: extra lgkm(0)+barrier after tile0 reads so p0(0)'s restage of B0(tile2)
//   cannot race another wave's prologue read of B0(tile0) (cross-wave drain).
// Swizzles (verified r2, conflicts=0): A chunk^(row&7) via pre-swizzled source;
// B stored pos (c+(row>>1))&3 via source bc=((t&3)-(t>>3))&3, read posq=(quad+(lrow>>1))&3.
// =====================================================================================
__global__ __launch_bounds__(512, 2) void gemm_qkv(
    const half_t* __restrict__ A,   // [M][K] = xh
    const half_t* __restrict__ Bt,  // [N][K] = Wqt
    const float* __restrict__ bias, // [N]
    const float* __restrict__ wq, const float* __restrict__ wk,
    half_t* __restrict__ Qh, half_t* __restrict__ Kh, half_t* __restrict__ Vt,
    int M, int N, int K)
{
    __shared__ __align__(16) half_t As[2][2][128 * 64];  // [buf][mhalf]
    __shared__ __align__(16) half_t Bs[2][2][256 * 32];  // [buf][khalf]

    int t = threadIdx.x;
    int lane = t & 63, w = t >> 6;
    int lrow = lane & 15, quad = lane >> 4;
    int wm = w >> 2, wn = w & 3;

    // XCD-aware swizzle (grid 384 % 8 == 0 -> simple form is bijective)
    int cpx = gridDim.x >> 3;
    int bid = blockIdx.x;
    int wg = (bid & 7) * cpx + (bid >> 3);
    int nbn = N >> 8;
    int mb = wg / nbn, nb = wg % nbn;
    int m0 = mb << 8, n0 = nb << 8;

    // ---- staging source pointers (source pre-swizzled to match read swizzles) ----
    int ar = t >> 3;                       // A: 64 rows/round, 8 chunks of 16B
    int ac = (t & 7) ^ (ar & 7);           // inverse of chunk ^ (row&7)
    const half_t* gAbase = A + (size_t)(m0 + ar) * K + ac * 8;
    int br = t >> 2;                       // B: 128 rows/round, 4 chunks of 16B
    int bc = ((t & 3) - (t >> 3)) & 3;     // inverse of c' = (c + (row>>1)) & 3
    const half_t* gBbase = Bt + (size_t)(n0 + br) * K + bc * 8;

    auto stageA = [&](int buf, int a, int T) {
        const half_t* s = gAbase + (size_t)a * 128 * K + T * 64;
        GLDS16(s,                  &As[buf][a][w * 512]);
        GLDS16(s + (size_t)64 * K, &As[buf][a][4096 + w * 512]);
    };
    auto stageB = [&](int buf, int kh, int T) {
        const half_t* s = gBbase + T * 64 + kh * 32;
        GLDS16(s,                   &Bs[buf][kh][w * 512]);
        GLDS16(s + (size_t)128 * K, &Bs[buf][kh][4096 + w * 512]);
    };

    // ---- ds_read offsets ----
    int sw = lrow & 7;
    int cx0 = ((0 + quad) ^ sw) * 8;       // A kk=0 chunk, swizzled
    int cx1 = ((4 + quad) ^ sw) * 8;       // A kk=1 chunk, swizzled
    int posq = (quad + (lrow >> 1)) & 3;   // B stored chunk position
    int aoffs = (wm * 64 + lrow) * 64;
    int boffs = (wn * 64 + lrow) * 32 + posq * 8;

    half8 af0[4], af1[4];                  // A frag sets (phase-alternating)
    half8 b0[4], b1[4];                    // B frags (rotate in place)
    float4v acc[2][4][4] = {};             // [ahalf][mi][ni]

    auto loadAk = [&](int buf, int a, int cx, half8 (&dst)[4]) {
        #pragma unroll
        for (int mi = 0; mi < 4; mi++)
            dst[mi] = *(const half8*)(&As[buf][a][aoffs + mi * 1024 + cx]);
    };
    auto loadBf = [&](int buf, int kh, half8 (&dst)[4]) {
        #pragma unroll
        for (int ni = 0; ni < 4; ni++)
            dst[ni] = *(const half8*)(&Bs[buf][kh][boffs + ni * 512]);
    };

#define MFMA16(AF, BF, AI)                                                        \
    do { _Pragma("unroll")                                                        \
        for (int mi = 0; mi < 4; mi++) { _Pragma("unroll")                        \
            for (int ni = 0; ni < 4; ni++)                                        \
                acc[AI][mi][ni] = __builtin_amdgcn_mfma_f32_16x16x32_f16(         \
                    AF[mi], BF[ni], acc[AI][mi][ni], 0, 0, 0);                    \
        } } while (0)

#define PH_TOP()                                                   \
    do {                                                           \
        __asm__ volatile("s_waitcnt lgkmcnt(0)" ::: "memory");     \
        __builtin_amdgcn_sched_barrier(0);                         \
    } while (0)
#define PH_BOT(STG)                                                               \
    do {                                                                          \
        __builtin_amdgcn_sched_barrier(0);                                        \
        if (STG) { __asm__ volatile("s_waitcnt vmcnt(6)" ::: "memory"); }         \
        else     { __asm__ volatile("s_waitcnt vmcnt(0)" ::: "memory"); }         \
        __asm__ volatile("s_barrier" ::: "memory");                               \
    } while (0)

    int nk = K >> 6;   // K-tiles of 64

    // ---- prologue: stage tiles 0,1 in ledger order [B0 B1 A0 A1], commit tile0 ----
    stageB(0, 0, 0); stageB(0, 1, 0); stageA(0, 0, 0); stageA(0, 1, 0);
    stageB(1, 0, 1); stageB(1, 1, 1); stageA(1, 0, 1); stageA(1, 1, 1);
    __asm__ volatile("s_waitcnt vmcnt(8)" ::: "memory");   // tile0 landed
    __asm__ volatile("s_barrier" ::: "memory");
    loadAk(0, 0, cx0, af0);        // p0 operands
    loadBf(0, 0, b0);
    // cross-wave drain of the prologue reads BEFORE p0(0) restages B0(tile2)
    __asm__ volatile("s_waitcnt lgkmcnt(0)" ::: "memory");
    __asm__ volatile("s_barrier" ::: "memory");

    for (int T = 0; T < nk; T++) {
        int buf = T & 1, nbuf = buf ^ 1;
        bool stg = (T + 2 < nk);
        bool rdn = (T + 1 < nk);

        // ---- p0: MFMA(A0k0, b0 -> acc0); read A1k0->af1, B1->b1; stage B0(T+2) ----
        PH_TOP();
        loadAk(buf, 1, cx0, af1);
        loadBf(buf, 1, b1);
        if (stg) stageB(buf, 0, T + 2);
        __builtin_amdgcn_sched_barrier(0);
        __builtin_amdgcn_s_setprio(1);
        MFMA16(af0, b0, 0);
        __builtin_amdgcn_s_setprio(0);
        PH_BOT(stg);

        // ---- p1: MFMA(A1k0, b0 -> acc1); read A0k1->af0; stage B1(T+2) ----
        PH_TOP();
        loadAk(buf, 0, cx1, af0);
        if (stg) stageB(buf, 1, T + 2);
        __builtin_amdgcn_sched_barrier(0);
        __builtin_amdgcn_s_setprio(1);
        MFMA16(af1, b0, 1);
        __builtin_amdgcn_s_setprio(0);
        PH_BOT(stg);

        // ---- p2: MFMA(A0k1, b1 -> acc0); read A1k1->af1, B0(T+1)->b0; stage A0(T+2) --
        PH_TOP();
        loadAk(buf, 1, cx1, af1);
        if (rdn) loadBf(nbuf, 0, b0);
        if (stg) stageA(buf, 0, T + 2);
        __builtin_amdgcn_sched_barrier(0);
        __builtin_amdgcn_s_setprio(1);
        MFMA16(af0, b1, 0);
        __builtin_amdgcn_s_setprio(0);
        PH_BOT(stg);

        // ---- p3: MFMA(A1k1, b1 -> acc1); read A0k0(T+1)->af0; stage A1(T+2) ----
        PH_TOP();
        if (rdn) loadAk(nbuf, 0, cx0, af0);
        if (stg) stageA(buf, 1, T + 2);
        __builtin_amdgcn_sched_barrier(0);
        __builtin_amdgcn_s_setprio(1);
        MFMA16(af1, b1, 1);
        __builtin_amdgcn_s_setprio(0);
        PH_BOT(stg);
    }

    // ---- epilogue: per-wave 64-col group = one head (Q/K rmsnorm) or V chunk ----
    int nglob = n0 + wn * 64;
    if (nglob < 2048) {
        int isK = nglob >> 10;
        int h = (nglob >> 6) & 15;
        const float* wv = isK ? wk : wq;
        half_t* dst = isK ? Kh : Qh;
        float post = isK ? 1.0f : LOG2E;   // pre-scale Q so attn works in log2 domain
        #pragma unroll
        for (int a = 0; a < 2; a++) {
            #pragma unroll
            for (int mi = 0; mi < 4; mi++) {
                #pragma unroll
                for (int r = 0; r < 4; r++) {
                    int gr = m0 + a * 128 + wm * 64 + mi * 16 + quad * 4 + r;
                    float v[4]; float ss = 0.f;
                    #pragma unroll
                    for (int ni = 0; ni < 4; ni++) {
                        v[ni] = acc[a][mi][ni][r] + bias[nglob + ni * 16 + lrow];
                        ss += v[ni] * v[ni];
                    }
                    ss += __shfl_xor(ss, 1);
                    ss += __shfl_xor(ss, 2);
                    ss += __shfl_xor(ss, 4);
                    ss += __shfl_xor(ss, 8);
                    float rr = rsqrtf(ss * (1.0f / 64.0f) + 1e-6f) * post;
                    int bb = gr >> 11, s = gr & 2047;
                    size_t rowbase = ((size_t)((bb * 16 + h) * 2048 + s)) * 64;
                    #pragma unroll
                    for (int ni = 0; ni < 4; ni++) {
                        int d = ni * 16 + lrow;
                        dst[rowbase + d] = (half_t)(v[ni] * rr * wv[d]);
                    }
                }
            }
        }
    } else {
        // V part: store transposed into Vt[bh][d][s]
        #pragma unroll
        for (int a = 0; a < 2; a++) {
            #pragma unroll
            for (int mi = 0; mi < 4; mi++) {
                int gr = m0 + a * 128 + wm * 64 + mi * 16 + quad * 4;   // s-base, 4-aligned
                int bb = gr >> 11, s = gr & 2047;
                #pragma unroll
                for (int ni = 0; ni < 4; ni++) {
                    int dg = nglob + ni * 16 + lrow - 2048;   // 0..1023
                    float bv = bias[nglob + ni * 16 + lrow];
                    half4v oh;
                    #pragma unroll
                    for (int r = 0; r < 4; r++) oh[r] = (half_t)(acc[a][mi][ni][r] + bv);
                    *(half4v*)(Vt + ((size_t)((bb * 16 + (dg >> 6)) * 64 + (dg & 63))) * 2048 + s) = oh;
                }
            }
        }
    }
#undef PH_TOP
#undef PH_BOT
#undef MFMA16
}

// ---------------- GEMM: C[M][N] = A[M][K] * Bt[N][K]^T + bias (output proj) ----------
// (r10 config: triple-buffered GLDS, raw barriers, bank-swizzle, 3 waves/SIMD)
template <int MODE>
__global__ __launch_bounds__(256, 3) void gemm_f16(
    const half_t* __restrict__ A,   // [M][K]
    const half_t* __restrict__ Bt,  // [N][K]
    const float* __restrict__ bias, // [N]
    void* __restrict__ Cout,
    int M, int N, int K,
    const float* __restrict__ wq, const float* __restrict__ wk,
    half_t* __restrict__ Qh, half_t* __restrict__ Kh)
{
    __shared__ __align__(16) half_t As[3][128 * 32];
    __shared__ __align__(16) half_t Bs[3][128 * 32];
    int t = threadIdx.x;
    int lane = t & 63, w = t >> 6;
    int m0 = blockIdx.x * 128, n0 = blockIdx.y * 128;
    int wm = (w >> 1) * 64, wn = (w & 1) * 64;
    int lrow = lane & 15, quad = lane >> 4;

    int lc = ((t & 3) - (t >> 3)) & 3;
    const half_t* gA = A  + (size_t)(m0 + (t >> 2)) * K + lc * 8;
    const half_t* gB = Bt + (size_t)(n0 + (t >> 2)) * K + lc * 8;
    half_t* ldsA[3] = { &As[0][w * 512], &As[1][w * 512], &As[2][w * 512] };
    half_t* ldsB[3] = { &Bs[0][w * 512], &Bs[1][w * 512], &Bs[2][w * 512] };

    int posq = (quad + (lrow >> 1)) & 3;

    float4v acc[4][4] = {};

    GLDS16(gA,                       ldsA[0]);
    GLDS16(gA + (size_t)64 * K,      ldsA[0] + 2048);
    GLDS16(gB,                       ldsB[0]);
    GLDS16(gB + (size_t)64 * K,      ldsB[0] + 2048);
    GLDS16(gA + 32,                  ldsA[1]);
    GLDS16(gA + (size_t)64 * K + 32, ldsA[1] + 2048);
    GLDS16(gB + 32,                  ldsB[1]);
    GLDS16(gB + (size_t)64 * K + 32, ldsB[1] + 2048);

    int nk = K >> 5;
    for (int ki = 0; ki < nk; ki++) {
        int cur = ki % 3, pre = (ki + 2) % 3;
        BAR_LGKM();
        if (ki + 2 < nk) {
            int kp = (ki + 2) << 5;
            GLDS16(gA + kp,                  ldsA[pre]);
            GLDS16(gA + (size_t)64 * K + kp, ldsA[pre] + 2048);
            GLDS16(gB + kp,                  ldsB[pre]);
            GLDS16(gB + (size_t)64 * K + kp, ldsB[pre] + 2048);
            BAR_VM(8);
        } else if (ki + 1 < nk) {
            BAR_VM(4);
        } else {
            BAR_VM(0);
        }
        half8 af[4], bf[4];
        for (int i = 0; i < 4; i++) af[i] = *(const half8*)(&As[cur][(wm + i * 16 + lrow) * 32 + posq * 8]);
        for (int i = 0; i < 4; i++) bf[i] = *(const half8*)(&Bs[cur][(wn + i * 16 + lrow) * 32 + posq * 8]);
        for (int mi = 0; mi < 4; mi++)
            for (int ni = 0; ni < 4; ni++)
                acc[mi][ni] = __builtin_amdgcn_mfma_f32_16x16x32_f16(af[mi], bf[ni], acc[mi][ni], 0, 0, 0);
    }

    if (MODE == 0) {
        float* out = (float*)Cout;
        for (int mi = 0; mi < 4; mi++)
            for (int ni = 0; ni < 4; ni++)
                for (int r = 0; r < 4; r++) {
                    int gr = m0 + wm + mi * 16 + quad * 4 + r;
                    int gc = n0 + wn + ni * 16 + lrow;
                    out[(size_t)gr * N + gc] = acc[mi][ni][r] + bias[gc];
                }
    } else {
        int nglob = n0 + wn;            // 64-aligned; one head per wave
        if (nglob < 2048) {
            int isK = nglob >> 10;
            int h = (nglob >> 6) & 15;
            const float* wv = isK ? wk : wq;
            half_t* dst = isK ? Kh : Qh;
            float post = isK ? 1.0f : LOG2E;
            for (int mi = 0; mi < 4; mi++)
                for (int r = 0; r < 4; r++) {
                    int gr = m0 + wm + mi * 16 + quad * 4 + r;
                    float v[4]; float ss = 0.f;
                    for (int ni = 0; ni < 4; ni++) {
                        v[ni] = acc[mi][ni][r] + bias[nglob + ni * 16 + lrow];
                        ss += v[ni] * v[ni];
                    }
                    ss += __shfl_xor(ss, 1);
                    ss += __shfl_xor(ss, 2);
                    ss += __shfl_xor(ss, 4);
                    ss += __shfl_xor(ss, 8);
                    float rr = rsqrtf(ss * (1.0f / 64.0f) + 1e-6f) * post;
                    int bb = gr >> 11, s = gr & 2047;
                    size_t rowbase = ((size_t)((bb * 16 + h) * 2048 + s)) * 64;
                    for (int ni = 0; ni < 4; ni++) {
                        int d = ni * 16 + lrow;
                        dst[rowbase + d] = (half_t)(v[ni] * rr * wv[d]);
                    }
                }
        } else {
            half_t* Vt = (half_t*)Cout;
            for (int mi = 0; mi < 4; mi++) {
                int gr = m0 + wm + mi * 16 + quad * 4;
                int bb = gr >> 11, s = gr & 2047;
                for (int ni = 0; ni < 4; ni++) {
                    int dg = nglob + ni * 16 + lrow - 2048;
                    float bv = bias[nglob + ni * 16 + lrow];
                    half4v oh;
                    for (int r = 0; r < 4; r++) oh[r] = (half_t)(acc[mi][ni][r] + bv);
                    *(half4v*)(Vt + ((size_t)((bb * 16 + (dg >> 6)) * 64 + (dg & 63))) * 2048 + s) = oh;
                }
            }
        }
    }
}

// ---------------- Flash attention, causal, no scale (Q pre-scaled by LOG2E) --
// 8 waves / 128 q-rows, paired q-tiles (i,15-i), grid (bh, pair) for XCD L2.
__global__ __launch_bounds__(512, 4) void attn(
    const half_t* __restrict__ Qh, const half_t* __restrict__ Kh, const half_t* __restrict__ Vt,
    half_t* __restrict__ Z)
{
    __shared__ __align__(16) half_t Ks[2][128 * 64];  // [buf][key][d], pos = chunk ^ (key&7)
    __shared__ __align__(16) half_t Vs[2][64 * 128];  // [buf][d][key], pos = chunk ^ (d&7)
    __shared__ __align__(16) half_t Ps[8][16 * 64];   // per-wave [q][key-half]

    int bh = blockIdx.x;
    int b = bh >> 4, h = bh & 15;
    int t = threadIdx.x, lane = t & 63, w = t >> 6;
    int lrow = lane & 15, quad = lane >> 4;

    int scc = (lane & 7) ^ ((lane >> 3) & 7);
    const half_t* gK0 = Kh + ((size_t)bh * 2048 + w * 16 + (lane >> 3)) * 64 + scc * 8;
    int vr0 = w * 8 + (lane >> 4);
    int vc0 = (lane & 15) ^ (lane >> 4);
    int vc1 = (lane & 15) ^ ((lane >> 4) + 4);
    const half_t* gV0 = Vt + ((size_t)bh * 64 + vr0) * 2048 + vc0 * 8;
    const half_t* gV1 = Vt + ((size_t)bh * 64 + vr0 + 4) * 2048 + vc1 * 8;
    half_t* ldsK[2] = { &Ks[0][w * 1024], &Ks[1][w * 1024] };
    half_t* ldsV[2] = { &Vs[0][w * 1024], &Vs[1][w * 1024] };

    int sw = lrow & 7;
    int cA = (quad ^ sw) * 8;
    int cB = ((quad + 4) ^ sw) * 8;
    half_t* PsW = &Ps[w][lrow * 64];

    for (int pass = 0; pass < 2; pass++) {
        int qt = pass ? (15 - (int)blockIdx.y) : (int)blockIdx.y;
        int q0w = qt * 128 + w * 16;

        const half_t* Qbase = Qh + ((size_t)bh * 2048 + q0w + lrow) * 64;
        half8 qf0 = *(const half8*)(Qbase + quad * 8);
        half8 qf1 = *(const half8*)(Qbase + 32 + quad * 8);

        float4v ot[4] = {};
        float m = -__builtin_inff(), l = 0.f;

        int nt = qt + 1;
        __syncthreads();
        GLDS16(gK0,       ldsK[0]);
        GLDS16(gK0 + 512, ldsK[0] + 512);
        GLDS16(gV0,       ldsV[0]);
        GLDS16(gV1,       ldsV[0] + 512);

        for (int kt = 0; kt < nt; kt++) {
            int cur = kt & 1, nxt = cur ^ 1;
            int kb = kt * 128;
            BAR_LGKM();
            if (kt + 1 < nt) {
                size_t ko = (size_t)(kb + 128);
                GLDS16(gK0 + ko * 64,       ldsK[nxt]);
                GLDS16(gK0 + ko * 64 + 512, ldsK[nxt] + 512);
                GLDS16(gV0 + ko,            ldsV[nxt]);
                GLDS16(gV1 + ko,            ldsV[nxt] + 512);
                BAR_VM(4);
            } else {
                BAR_VM(0);
            }

            float4v st[8];
            for (int f = 0; f < 8; f++) {
                float4v z = {};
                const half_t* kr = &Ks[cur][(f * 16 + lrow) * 64];
                half8 k0 = *(const half8*)(kr + cA);
                half8 k1 = *(const half8*)(kr + cB);
                z = __builtin_amdgcn_mfma_f32_16x16x32_f16(k0, qf0, z, 0, 0, 0);
                z = __builtin_amdgcn_mfma_f32_16x16x32_f16(k1, qf1, z, 0, 0, 0);
                st[f] = z;
            }
            if (kb + 127 > q0w) {
                int qabs = q0w + lrow;
                for (int f = 0; f < 8; f++)
                    for (int r = 0; r < 4; r++) {
                        int key = kb + f * 16 + quad * 4 + r;
                        if (key > qabs) st[f][r] = -__builtin_inff();
                    }
            }
            float tm = st[0][0];
            for (int f = 0; f < 8; f++)
                for (int r = 0; r < 4; r++) tm = fmaxf(tm, st[f][r]);
            tm = fmaxf(tm, __shfl_xor(tm, 16));
            tm = fmaxf(tm, __shfl_xor(tm, 32));
            float mn = fmaxf(m, tm);
            float alpha = __builtin_amdgcn_exp2f(m - mn);
            m = mn;
            float rs = 0.f;
            uint2 pw1[4];
            for (int f = 0; f < 8; f++) {
                float p0 = __builtin_amdgcn_exp2f(st[f][0] - mn);
                float p1 = __builtin_amdgcn_exp2f(st[f][1] - mn);
                float p2 = __builtin_amdgcn_exp2f(st[f][2] - mn);
                float p3 = __builtin_amdgcn_exp2f(st[f][3] - mn);
                rs += (p0 + p1) + (p2 + p3);
                uint2 pw;
                pw.x = __builtin_bit_cast(unsigned, __builtin_amdgcn_cvt_pkrtz(p0, p1));
                pw.y = __builtin_bit_cast(unsigned, __builtin_amdgcn_cvt_pkrtz(p2, p3));
                if (f < 4) {
                    int cc = (2 * f + (quad >> 1)) ^ sw;
                    *(uint2*)(PsW + cc * 8 + (quad & 1) * 4) = pw;
                } else {
                    pw1[f - 4] = pw;
                }
            }
            rs += __shfl_xor(rs, 16);
            rs += __shfl_xor(rs, 32);
            l = l * alpha + rs;
            for (int f2 = 0; f2 < 4; f2++)
                for (int r = 0; r < 4; r++) ot[f2][r] *= alpha;

            __asm__ volatile("s_waitcnt lgkmcnt(0)" ::: "memory");
            half8 p0v = *(const half8*)(PsW + cA);
            half8 p1v = *(const half8*)(PsW + cB);
            for (int f2 = 0; f2 < 4; f2++) {
                int row = f2 * 16 + lrow;
                half8 v0 = *(const half8*)(&Vs[cur][row * 128 + ((quad ^ sw)) * 8]);
                half8 v1 = *(const half8*)(&Vs[cur][row * 128 + (((4 + quad) ^ sw)) * 8]);
                ot[f2] = __builtin_amdgcn_mfma_f32_16x16x32_f16(v0, p0v, ot[f2], 0, 0, 0);
                ot[f2] = __builtin_amdgcn_mfma_f32_16x16x32_f16(v1, p1v, ot[f2], 0, 0, 0);
            }
            for (int f = 0; f < 4; f++) {
                int cc = (2 * f + (quad >> 1)) ^ sw;
                *(uint2*)(PsW + cc * 8 + (quad & 1) * 4) = pw1[f];
            }
            __asm__ volatile("s_waitcnt lgkmcnt(0)" ::: "memory");
            half8 p2v = *(const half8*)(PsW + cA);
            half8 p3v = *(const half8*)(PsW + cB);
            for (int f2 = 0; f2 < 4; f2++) {
                int row = f2 * 16 + lrow;
                half8 v2 = *(const half8*)(&Vs[cur][row * 128 + (((8 + quad) ^ sw)) * 8]);
                half8 v3 = *(const half8*)(&Vs[cur][row * 128 + (((12 + quad) ^ sw)) * 8]);
                ot[f2] = __builtin_amdgcn_mfma_f32_16x16x32_f16(v2, p2v, ot[f2], 0, 0, 0);
                ot[f2] = __builtin_amdgcn_mfma_f32_16x16x32_f16(v3, p3v, ot[f2], 0, 0, 0);
            }
        }

        float inv = 1.0f / l;
        size_t base = ((size_t)(b * 2048) + q0w + lrow) * 1024 + h * 64;
        for (int f2 = 0; f2 < 4; f2++) {
            half4v oh;
            for (int r = 0; r < 4; r++) oh[r] = (half_t)(ot[f2][r] * inv);
            *(half4v*)(Z + base + f2 * 16 + quad * 4) = oh;
        }
    }
}

// ---------------- launch ----------------
extern "C" void kernel_launch(void* const* d_in, const int* in_sizes, int n_in,
                              void* d_out, int out_size, void* d_ws, size_t ws_size,
                              hipStream_t stream)
{
    const float* x     = (const float*)d_in[0];
    // d_in[1] = mask (causal, known analytically) - unused
    const float* W_qkv = (const float*)d_in[2];
    const float* b_qkv = (const float*)d_in[3];
    const float* W_o   = (const float*)d_in[4];
    const float* b_o   = (const float*)d_in[5];
    const float* wq    = (const float*)d_in[6];
    const float* wk    = (const float*)d_in[7];
    float* out = (float*)d_out;

    char* ws = (char*)d_ws;
    half_t* xh   = (half_t*)(ws);                     // 16 MB (reused as zh after attn)
    half_t* Wqt  = (half_t*)(ws + (16ull << 20));     // 6 MB
    half_t* Wot  = (half_t*)(ws + (22ull << 20));     // 2 MB
    half_t* Qh   = (half_t*)(ws + (40ull << 20));     // 16 MB
    half_t* Kh   = (half_t*)(ws + (56ull << 20));     // 16 MB
    half_t* Vt   = (half_t*)(ws + (72ull << 20));     // 16 MB
    half_t* zh   = xh;

    cast_f32_f16<<<8192, 256, 0, stream>>>(x, xh, 8192 * 1024);
    transpose_cast<<<dim3(96, 32), dim3(32, 8), 0, stream>>>(W_qkv, Wqt, 1024, 3072);
    transpose_cast<<<dim3(32, 32), dim3(32, 8), 0, stream>>>(W_o, Wot, 1024, 1024);
    gemm_qkv<<<384, 512, 0, stream>>>(xh, Wqt, b_qkv, wq, wk, Qh, Kh, Vt, 8192, 3072, 1024);
    attn<<<dim3(64, 8), 512, 0, stream>>>(Qh, Kh, Vt, zh);
    gemm_f16<0><<<dim3(64, 8), 256, 0, stream>>>(zh, Wot, b_o, out, 8192, 1024, 1024,
                                                 nullptr, nullptr, nullptr, nullptr);
}